// Round 3
// baseline (303.452 us; speedup 1.0000x reference)
//
#include <hip/hip_runtime.h>
#include <hip/hip_bf16.h>
#include <stdint.h>
#include <string.h>

// Problem constants (fixed by the reference)
#define NUM_CHIPS 4
#define N_EXPERTS 32
#define TOP_K 4
#define SEQ 1024
#define HIDDEN 2048
#define MAX_TOK 1024
#define META_LEN 8
#define NPC (SEQ * TOP_K)            // 4096 assignments per chip
#define NTOT (NUM_CHIPS * NPC)       // 16384 assignments total
#define ROWS (N_EXPERTS * MAX_TOK)   // 32768 output rows
#define BUF_ELEMS ((size_t)ROWS * HIDDEN)           // 67,108,864
#define META_OFF BUF_ELEMS
#define CNT_OFF (BUF_ELEMS + (size_t)ROWS * META_LEN)

// Workspace layout (ints)
#define WS_RANK 0                    // [NTOT]   within-chip stable rank
#define WS_CNT  (NTOT)               // [4][32]  per-chip per-expert counts

#define OCC_ITEMS (NUM_CHIPS * SEQ)  // 4096 token items
#define EMPTY_ITEMS (ROWS / 4)       // 8192 zero-fill items (4 rows each)
#define TOTAL_BLOCKS (OCC_ITEMS + EMPTY_ITEMS)  // 12288

typedef float vfloat4 __attribute__((ext_vector_type(4)));

// ---------------------------------------------------------------------------
// rank_kernel: one block per chip, 1024 threads. All 4096 expert ids loaded
// into registers up-front; 4 serial chunk iterations of ballot-rank +
// 16-wave LDS scan. Produces within-chip stable rank per assignment and the
// per-chip per-expert counts. ~4 us. (unchanged)
// ---------------------------------------------------------------------------
__global__ __launch_bounds__(1024) void rank_kernel(const int* __restrict__ idx,
                                                    int* __restrict__ ws) {
    __shared__ int run_base[N_EXPERTS];       // running per-expert count
    __shared__ int wave_cnt[16][N_EXPERTS];   // per-wave group sizes in chunk
    __shared__ int wave_base[16][N_EXPERTS];  // exclusive base per wave

    const int c = blockIdx.x;
    const int t = threadIdx.x;
    const int lane = t & 63;
    const int w = t >> 6;

    int e[4];
#pragma unroll
    for (int q = 0; q < 4; ++q) e[q] = idx[c * NPC + q * 1024 + t];

    if (t < N_EXPERTS) run_base[t] = 0;
    __syncthreads();

#pragma unroll
    for (int q = 0; q < 4; ++q) {
        if (t < 16 * N_EXPERTS) ((int*)wave_cnt)[t] = 0;
        __syncthreads();

        // mask of lanes in this wave routed to the same expert
        uint64_t m = ~0ull;
#pragma unroll
        for (int b = 0; b < 5; ++b) {
            uint64_t bb = __ballot((e[q] >> b) & 1);
            m &= ((e[q] >> b) & 1) ? bb : ~bb;
        }
        const int rk = __popcll(m & ((1ull << lane) - 1ull));  // stable in-wave rank
        if (rk == 0) wave_cnt[w][e[q]] = __popcll(m);          // group leader
        __syncthreads();

        // cross-wave exclusive scan per expert, update running base
        if (t < N_EXPERTS) {
            int s = run_base[t];
#pragma unroll
            for (int ww = 0; ww < 16; ++ww) {
                wave_base[ww][t] = s;
                s += wave_cnt[ww][t];
            }
            run_base[t] = s;
        }
        __syncthreads();

        ws[WS_RANK + c * NPC + q * 1024 + t] = wave_base[w][e[q]] + rk;
        // next writes to wave_base occur only after two more __syncthreads().
    }
    __syncthreads();
    if (t < N_EXPERTS) ws[WS_CNT + c * N_EXPERTS + t] = run_base[t];
}

// ---------------------------------------------------------------------------
// scatter_all: fused occ-scatter + empty-zero-fill, role-INTERLEAVED so the
// x read stream (32 MB, read-once) is spread uniformly across the dispatch
// instead of concentrated in the first third (better sustained mixed R/W
// DRAM efficiency). x rows are loaded nontemporally (read exactly once —
// caching them only evicts freshly-dirtied output lines). Cross-chip prefix
// offsets and per-expert totals are precomputed once per block (single
// barrier, no inner chip loop).
//   block b: b%3==0 -> occ item b/3 (one (chip,token): read 8KB once,
//                      write its K=4 destination rows)
//            else   -> empty item (4 rows, zero-fill where slot >= tot[e])
// ---------------------------------------------------------------------------
__global__ __launch_bounds__(256) void scatter_all(const float* __restrict__ x,
                                                   const float* __restrict__ wts,
                                                   const int* __restrict__ idx,
                                                   const int* __restrict__ ws,
                                                   float* __restrict__ out) {
    __shared__ int base_s[NUM_CHIPS * N_EXPERTS];  // exclusive cross-chip offsets
    __shared__ int tot_s[N_EXPERTS];               // per-expert totals
    const int t = threadIdx.x;
    const int bid = blockIdx.x;

    if (t < N_EXPERTS) {
        const int c0 = ws[WS_CNT + t];
        const int c1 = ws[WS_CNT + N_EXPERTS + t];
        const int c2 = ws[WS_CNT + 2 * N_EXPERTS + t];
        const int c3 = ws[WS_CNT + 3 * N_EXPERTS + t];
        base_s[t] = 0;
        base_s[N_EXPERTS + t] = c0;
        base_s[2 * N_EXPERTS + t] = c0 + c1;
        base_s[3 * N_EXPERTS + t] = c0 + c1 + c2;
        tot_s[t] = c0 + c1 + c2 + c3;
    }
    __syncthreads();

    const int q = bid / 3;
    const int r = bid - 3 * q;

    if (r == 0) {
        // ---------------- occ item q: token-driven scatter ----------------
        const int c = q >> 10;                 // chip
        const int tk = q & (SEQ - 1);          // token

        if (q == 0 && t < N_EXPERTS)
            out[CNT_OFF + t] = (float)tot_s[t];  // experts_counter output

        const vfloat4* src = (const vfloat4*)(x + ((size_t)c * SEQ + tk) * HIDDEN);
        vfloat4 v0 = __builtin_nontemporal_load(src + t);
        vfloat4 v1 = __builtin_nontemporal_load(src + t + 256);

        int e[TOP_K], rk[TOP_K];
#pragma unroll
        for (int k = 0; k < TOP_K; ++k) {
            e[k] = idx[c * NPC + tk * TOP_K + k];
            rk[k] = ws[WS_RANK + c * NPC + tk * TOP_K + k];
        }

#pragma unroll
        for (int k = 0; k < TOP_K; ++k) {
            const int row = e[k] * MAX_TOK + base_s[c * N_EXPERTS + e[k]] + rk[k];

            vfloat4* dst = (vfloat4*)(out + (size_t)row * HIDDEN);
            dst[t] = v0;
            dst[t + 256] = v1;

            if (t < META_LEN) {
                float mv = 0.0f;
                if (t == 0) mv = (float)c;
                else if (t == 1) mv = (float)tk;
                else if (t == 2) mv = (float)k;
                else if (t == 3) mv = (float)e[k];
                else if (t == 4) {
                    // bf16 bits of the routing weight, RNE (matches jax astype)
                    float wv = wts[c * NPC + tk * TOP_K + k];
                    uint32_t ub;
                    memcpy(&ub, &wv, 4);
                    uint32_t lsb = (ub >> 16) & 1u;
                    uint32_t bits = (ub + 0x7FFFu + lsb) >> 16;
                    mv = (float)(int)(short)(uint16_t)bits;  // sign-extend int16
                }
                out[META_OFF + (size_t)row * META_LEN + t] = mv;
            }
        }
    } else {
        // ---------------- empty item: zero-fill 4 rows ----------------
        const int g = 2 * q + (r - 1);            // empty group in [0, 8192)
        const int row0 = g * 4;
        const int e = row0 >> 10;
        const int slot0 = row0 & (MAX_TOK - 1);
        const int tot = tot_s[e];

        if (slot0 + 3 < tot) return;              // fully occupied group

        const vfloat4 z = (vfloat4)(0.f);
#pragma unroll
        for (int rr = 0; rr < 4; ++rr) {
            if (slot0 + rr < tot) continue;       // occupied row handled by occ role
            vfloat4* dst = (vfloat4*)(out + (size_t)(row0 + rr) * HIDDEN);
            dst[t] = z;
            dst[t + 256] = z;
            if (t < META_LEN)
                out[META_OFF + (size_t)(row0 + rr) * META_LEN + t] = -1.0f;
        }
    }
}

extern "C" void kernel_launch(void* const* d_in, const int* in_sizes, int n_in,
                              void* d_out, int out_size, void* d_ws, size_t ws_size,
                              hipStream_t stream) {
    const float* x   = (const float*)d_in[0];   // [4,1024,2048] f32
    const float* wts = (const float*)d_in[1];   // [4,1024,4]    f32
    const int*   idx = (const int*)d_in[2];     // [4,1024,4]    i32
    float* out = (float*)d_out;
    int* ws = (int*)d_ws;

    rank_kernel<<<NUM_CHIPS, 1024, 0, stream>>>(idx, ws);
    scatter_all<<<TOTAL_BLOCKS, 256, 0, stream>>>(x, wts, idx, ws, out);
}